// Round 16
// baseline (161.733 us; speedup 1.0000x reference)
//
#include <hip/hip_runtime.h>
#include <stdint.h>

#define HW 16384
#define CH 384
#define NS 32

typedef float  f32x4  __attribute__((ext_vector_type(4)));
typedef short  short8 __attribute__((ext_vector_type(8)));
typedef __bf16 bf16x8 __attribute__((ext_vector_type(8)));
typedef unsigned short u16;
typedef u16 u16x4 __attribute__((ext_vector_type(4)));
typedef u16 u16x8 __attribute__((ext_vector_type(8)));

__device__ __forceinline__ u16 f2bf(float f) {
  union { float f; uint32_t u; } v; v.f = f;
  uint32_t r = v.u + 0x7fffu + ((v.u >> 16) & 1u);
  return (u16)(r >> 16);
}
__device__ __forceinline__ float bf2f(u16 v) {
  union { uint32_t u; float f; } x; x.u = ((uint32_t)v) << 16; return x.f;
}
__device__ __forceinline__ f32x4 zero4() { f32x4 z = {0.f, 0.f, 0.f, 0.f}; return z; }

__device__ __forceinline__ f32x4 mfma_bf16(short8 a, short8 b, f32x4 c) {
  return __builtin_amdgcn_mfma_f32_16x16x32_bf16(
      __builtin_bit_cast(bf16x8, a), __builtin_bit_cast(bf16x8, b), c, 0, 0, 0);
}

__device__ __forceinline__ void gload16(const void* g, void* lds) {
  auto gp = (const __attribute__((address_space(1))) uint32_t*)(uintptr_t)g;
  auto lp = (__attribute__((address_space(3))) uint32_t*)(uintptr_t)lds;
  __builtin_amdgcn_global_load_lds(gp, lp, 16, 0, 0);
}

// ---- k_conv: pure streaming converts (proven R13) ---------------------------
// blocks 0..1535: x fp32 -> xb bf16; 1536..3263: qkv_w -> wbf; 3264..3299: WvT.
__global__ __launch_bounds__(256) void k_conv(const float* __restrict__ x,
                                              u16* __restrict__ xb,
                                              const float* __restrict__ w,
                                              u16* __restrict__ wbf,
                                              u16* __restrict__ wvt) {
  const int bid = blockIdx.x, t = threadIdx.x;
  if (bid < 1536) {
    const float* src = x + (size_t)bid * 16384;
    u16x4* dst = (u16x4*)(xb + (size_t)bid * 16384);
#pragma unroll
    for (int j = 0; j < 8; ++j) {
      f32x4 a = *(const f32x4*)(src + 4 * (j * 512 + t));
      f32x4 b = *(const f32x4*)(src + 4 * (j * 512 + 256 + t));
      u16x4 pa, pb;
#pragma unroll
      for (int i = 0; i < 4; ++i) { pa[i] = f2bf(a[i]); pb[i] = f2bf(b[i]); }
      dst[j * 512 + t] = pa;
      dst[j * 512 + 256 + t] = pb;
    }
    return;
  }
  if (bid < 3264) {
    const int i = (bid - 1536) * 256 + t;
    wbf[i] = f2bf(w[i]);
    return;
  }
  __shared__ u16 tl[64][66];
  const int q = bid - 3264;
  const int ci = q % 6, di = q / 6;
#pragma unroll
  for (int jj = 0; jj < 4; ++jj) {
    const int r = (t >> 4) + jj * 16;
    f32x4 v = *(const f32x4*)(w + (size_t)(768 + di * 64 + r) * CH + ci * 64 + (t & 15) * 4);
#pragma unroll
    for (int i = 0; i < 4; ++i) tl[(t & 15) * 4 + i][r] = f2bf(v[i]);
  }
  __syncthreads();
#pragma unroll
  for (int jj = 0; jj < 2; ++jj) {
    const int c = (t >> 3) + jj * 32;
    short8 v = *(const short8*)(&tl[c][(t & 7) * 8]);
    *(short8*)(wvt + (size_t)(ci * 64 + c) * CH + di * 64 + (t & 7) * 8) = v;
  }
}

// ---- stage 128 rows x 32 k, paired-row LDS, proven 0-conflict (R5/R6) -------
template <int STRIDE>
__device__ __forceinline__ void stageS(u16* lds, const u16* __restrict__ g, int t) {
  const int w = t >> 6;
#pragma unroll
  for (int s = 0; s < 2; ++s) {
    const int r = s * 32 + (t >> 3);
    const int g8 = (t & 7) ^ (r & 7);
    const int gr = 2 * r + (g8 >> 2);
    gload16(g + (size_t)gr * STRIDE + (g8 & 3) * 8, lds + s * 2048 + w * 512);
  }
}

// ---- k_xform: fused gram-of-x (blocks 0..767) + bf16 transpose (768..3839) --
// gramx (proven R9-R15): staged ring-3 MFMA, uses 48 KB LDS. tb16 (proven R13):
// 128n x 64c tiles, [128][66] pad (b128 read 2-way free). The transpose's
// memory time hides under gramx's MFMA/LDS-bound blocks (grid concurrency).
__global__ __launch_bounds__(256) void k_xform(const u16* __restrict__ xb,
                                               float* __restrict__ part,
                                               u16* __restrict__ xT) {
  __shared__ u16 smem[24576];  // 48 KB, union of both branches
  const int bid = blockIdx.x, t = threadIdx.x;
  if (bid < 768) {
    // ---- gramx ----
    const int L = (bid & 7) * 96 + (bid >> 3);   // bijective XCD chunk (768%8==0)
    const int pair = L % 6;
    const int ns = (L / 6) % NS;
    const int b = L / (6 * NS);
    const int i = pair < 3 ? 0 : (pair < 5 ? 1 : 2);
    const int j = pair < 3 ? pair : (pair < 5 ? pair - 2 : 2);
    const int lane = t & 63, w = t >> 6;
    const int wo = w & 1, wn = w >> 1;
    const u16* pa = xb + ((size_t)b * CH + i * 128) * HW + ns * 512;
    const u16* pb = xb + ((size_t)b * CH + j * 128) * HW + ns * 512;
    u16* As = smem;           // 3 x 4096 u16
    u16* Bs = smem + 12288;   // 3 x 4096 u16

    f32x4 acc[4][4];
#pragma unroll
    for (int a = 0; a < 4; ++a)
#pragma unroll
      for (int c = 0; c < 4; ++c) acc[a][c] = zero4();

#pragma unroll
    for (int p = 0; p < 2; ++p) {
      stageS<HW>(As + p * 4096, pa + p * 32, t);
      stageS<HW>(Bs + p * 4096, pb + p * 32, t);
    }
    const int ks = lane >> 4;
    for (int kt = 0; kt < 16; ++kt) {
      if (kt < 15) asm volatile("s_waitcnt vmcnt(4)" ::: "memory");
      else         asm volatile("s_waitcnt vmcnt(0)" ::: "memory");
      asm volatile("s_barrier" ::: "memory");
      if (kt <= 13) {
        stageS<HW>(As + ((kt + 2) % 3) * 4096, pa + (kt + 2) * 32, t);
        stageS<HW>(Bs + ((kt + 2) % 3) * 4096, pb + (kt + 2) * 32, t);
      }
      const u16* Ac = As + (kt % 3) * 4096;
      const u16* Bc = Bs + (kt % 3) * 4096;
      short8 af[4], bf[4];
#pragma unroll
      for (int mi = 0; mi < 4; ++mi) {
        const int gr = wo * 64 + mi * 16 + (lane & 15);
        const int r = gr >> 1;
        const int p = ((gr & 1) * 4 + ks) ^ (r & 7);
        af[mi] = *(const short8*)(Ac + r * 64 + p * 8);
      }
#pragma unroll
      for (int ni = 0; ni < 4; ++ni) {
        const int gr = wn * 64 + ni * 16 + (lane & 15);
        const int r = gr >> 1;
        const int p = ((gr & 1) * 4 + ks) ^ (r & 7);
        bf[ni] = *(const short8*)(Bc + r * 64 + p * 8);
      }
#pragma unroll
      for (int ni = 0; ni < 4; ++ni)
#pragma unroll
        for (int mi = 0; mi < 4; ++mi)
          acc[ni][mi] = mfma_bf16(bf[ni], af[mi], acc[ni][mi]);
    }
    float* dst = part + ((size_t)(b * 6 + pair) * NS + ns) * 16384;
#pragma unroll
    for (int ni = 0; ni < 4; ++ni)
#pragma unroll
      for (int mi = 0; mi < 4; ++mi) {
        const int ai = wo * 64 + mi * 16 + (lane & 15);
        const int bj = wn * 64 + ni * 16 + ((lane >> 4) << 2);
        *(f32x4*)(dst + (size_t)ai * 128 + bj) = acc[ni][mi];
      }
  } else {
    // ---- tb16: xb[b][c][n] -> xT[b][n][c], 128n x 64c tile ----
    const int q = bid - 768;
    const int b = q / 768;
    const int rem = q % 768;
    const int nt = rem % 128;
    const int cq = rem / 128;
    const int c0 = cq * 64, n0 = nt * 128;
    u16 (*tile)[66] = (u16(*)[66])smem;  // 128 x 66 = 16.5 KB
    const u16* src = xb + (size_t)b * CH * HW;
#pragma unroll
    for (int p = 0; p < 4; ++p) {
      const int u = p * 256 + t;
      const int c = u >> 4, nc = u & 15;
      u16x8 v = *(const u16x8*)(src + (size_t)(c0 + c) * HW + n0 + nc * 8);
#pragma unroll
      for (int i = 0; i < 8; ++i) tile[nc * 8 + i][c] = v[i];
    }
    __syncthreads();
    u16* dst = xT + (size_t)b * HW * CH;
#pragma unroll
    for (int p = 0; p < 4; ++p) {
      const int u = p * 256 + t;
      const int r = u >> 3, cc = u & 7;
      short8 v = *(const short8*)(&tile[r][cc * 8]);
      *(short8*)(dst + (size_t)(n0 + r) * CH + c0 + cc * 8) = v;
    }
  }
}

// ---- reduce partials -> Goff bf16 (diag zeroed, mirrored) + Gd f32 ----------
__global__ __launch_bounds__(256) void k_greduce(const float* __restrict__ part,
                                                 u16* __restrict__ Goff,
                                                 float* __restrict__ Gd) {
  const int cq = blockIdx.x, pair = blockIdx.y, b = blockIdx.z;
  const int i = pair < 3 ? 0 : (pair < 5 ? 1 : 2);
  const int j = pair < 3 ? pair : (pair < 5 ? pair - 2 : 2);
  const int t = threadIdx.x;
  const int c0 = cq * 16;
  __shared__ u16 tl[16][136];
  const float* src = part + (size_t)(b * 6 + pair) * NS * 16384;
#pragma unroll
  for (int p = 0; p < 2; ++p) {
    const int q = t + p * 256;
    const int ai = q >> 2;
    const int bj = c0 + (q & 3) * 4;
    f32x4 s = zero4();
    for (int ns = 0; ns < NS; ++ns) s += *(const f32x4*)(src + (size_t)ns * 16384 + ai * 128 + bj);
    if (i == j) {
#pragma unroll
      for (int jj = 0; jj < 4; ++jj)
        if (ai == bj + jj) { Gd[b * CH + i * 128 + ai] = s[jj]; s[jj] = 0.f; }
    }
    u16x4 pk;
#pragma unroll
    for (int jj = 0; jj < 4; ++jj) { pk[jj] = f2bf(s[jj]); tl[bj - c0 + jj][ai] = pk[jj]; }
    *(u16x4*)(Goff + ((size_t)b * CH + i * 128 + ai) * CH + j * 128 + bj) = pk;
  }
  if (i != j) {
    __syncthreads();
    const int r = t >> 4;
    const int ch = (t & 15) * 8;
    short8 v = *(const short8*)(&tl[r][ch]);
    *(short8*)(Goff + ((size_t)b * CH + j * 128 + c0 + r) * CH + i * 128 + ch) = v;
  }
}

// ---- mini GEMM 128x128, K=384: C = A x B^T (B rows k-contig), ring-4 --------
template <int TM>
__global__ __launch_bounds__(256) void k_mini(const u16* __restrict__ A,
                                              const u16* __restrict__ B,
                                              float* __restrict__ Tout,
                                              u16* __restrict__ Bout,
                                              const float* __restrict__ Gd,
                                              const u16* __restrict__ Wd) {
  const int nt = blockIdx.x, mt = blockIdx.y, b = blockIdx.z;
  __shared__ u16 Ws[4][64 * 64];
  __shared__ u16 Xs[4][64 * 64];
  const int t = threadIdx.x, lane = t & 63, w = t >> 6;
  const int wo = w & 1, wn = w >> 1;
  const u16* Ab = A + (TM ? 0 : (size_t)b * CH * CH) + (size_t)mt * 128 * CH;
  const u16* Bb = B + (TM ? (size_t)b * CH * CH : 0) + (size_t)nt * 128 * CH;

  f32x4 acc[4][4];
#pragma unroll
  for (int a = 0; a < 4; ++a)
#pragma unroll
    for (int c = 0; c < 4; ++c) acc[a][c] = zero4();

#pragma unroll
  for (int p = 0; p < 3; ++p) {
    stageS<CH>(Ws[p], Ab + p * 32, t);
    stageS<CH>(Xs[p], Bb + p * 32, t);
  }
  const int ks = lane >> 4;
  for (int kt = 0; kt < 12; ++kt) {
    if (kt <= 9)       asm volatile("s_waitcnt vmcnt(8)" ::: "memory");
    else if (kt == 10) asm volatile("s_waitcnt vmcnt(4)" ::: "memory");
    else               asm volatile("s_waitcnt vmcnt(0)" ::: "memory");
    asm volatile("s_barrier" ::: "memory");
    if (kt < 9) {
      stageS<CH>(Ws[(kt + 3) & 3], Ab + (kt + 3) * 32, t);
      stageS<CH>(Xs[(kt + 3) & 3], Bb + (kt + 3) * 32, t);
    }
    const u16* Wc = Ws[kt & 3];
    const u16* Xc = Xs[kt & 3];
    short8 af[4], bfr[4];
#pragma unroll
    for (int mi = 0; mi < 4; ++mi) {
      const int gr = wo * 64 + mi * 16 + (lane & 15);
      const int r = gr >> 1;
      const int p = ((gr & 1) * 4 + ks) ^ (r & 7);
      af[mi] = *(const short8*)(Wc + r * 64 + p * 8);
    }
#pragma unroll
    for (int ni = 0; ni < 4; ++ni) {
      const int gr = wn * 64 + ni * 16 + (lane & 15);
      const int r = gr >> 1;
      const int p = ((gr & 1) * 4 + ks) ^ (r & 7);
      bfr[ni] = *(const short8*)(Xc + r * 64 + p * 8);
    }
#pragma unroll
    for (int ni = 0; ni < 4; ++ni)
#pragma unroll
      for (int mi = 0; mi < 4; ++mi)
        acc[ni][mi] = mfma_bf16(bfr[ni], af[mi], acc[ni][mi]);
  }

#pragma unroll
  for (int ni = 0; ni < 4; ++ni)
#pragma unroll
    for (int mi = 0; mi < 4; ++mi) {
      const int tr = mt * 128 + wo * 64 + mi * 16 + (lane & 15);
      const int d0 = nt * 128 + wn * 64 + ni * 16 + ((lane >> 4) << 2);
      if (TM) {
        f32x4 g = *(const f32x4*)(Gd + b * CH + d0);
        u16x4 w4 = *(const u16x4*)(Wd + (size_t)tr * CH + d0);
        f32x4 v;
#pragma unroll
        for (int jj = 0; jj < 4; ++jj) v[jj] = acc[ni][mi][jj] + bf2f(w4[jj]) * g[jj];
        *(f32x4*)(Tout + ((size_t)b * 768 + tr) * CH + d0) = v;
      } else {
        u16x4 pk;
#pragma unroll
        for (int jj = 0; jj < 4; ++jj) pk[jj] = f2bf(acc[ni][mi][jj]);
        *(u16x4*)(Bout + ((size_t)b * CH + tr) * CH + d0) = pk;
      }
    }
}

// ---- per (b,h): S = T1*Wk^T (MFMA, wave0) ; norms ; softmax ; M = proj∘attn -
__global__ __launch_bounds__(384) void k_attn(const float* __restrict__ T,
                                              const u16* __restrict__ wbf,
                                              const float* __restrict__ projw,
                                              const float* __restrict__ temp,
                                              u16* __restrict__ Mbf) {
  const int h = blockIdx.x, b = blockIdx.y, t = threadIdx.x;
  __shared__ float Sl[48][48];
  __shared__ float attn[48][48];
  __shared__ float nrm[96];
  const float* T1 = T + ((size_t)b * 768 + h * 48) * CH;
  const float* T2 = T1 + (size_t)384 * CH;
  const u16* wk = wbf + (size_t)(384 + h * 48) * CH;

  if (t < 64) {
    const int lane = t;
    f32x4 sa[3][3];
#pragma unroll
    for (int a = 0; a < 3; ++a)
#pragma unroll
      for (int c = 0; c < 3; ++c) sa[a][c] = zero4();
    for (int kk = 0; kk < 12; ++kk) {
      const int kc = kk * 32 + ((lane >> 4) << 3);
      short8 afr[3], bfr[3];
#pragma unroll
      for (int mi = 0; mi < 3; ++mi) {
        const float* s = T1 + (size_t)(mi * 16 + (lane & 15)) * CH + kc;
        f32x4 v0 = *(const f32x4*)(s);
        f32x4 v1 = *(const f32x4*)(s + 4);
        short8 a;
#pragma unroll
        for (int jj = 0; jj < 4; ++jj) { a[jj] = (short)f2bf(v0[jj]); a[4 + jj] = (short)f2bf(v1[jj]); }
        afr[mi] = a;
      }
#pragma unroll
      for (int ni = 0; ni < 3; ++ni)
        bfr[ni] = *(const short8*)(wk + (size_t)(ni * 16 + (lane & 15)) * CH + kc);
#pragma unroll
      for (int ni = 0; ni < 3; ++ni)
#pragma unroll
        for (int mi = 0; mi < 3; ++mi)
          sa[ni][mi] = mfma_bf16(bfr[ni], afr[mi], sa[ni][mi]);
    }
#pragma unroll
    for (int ni = 0; ni < 3; ++ni)
#pragma unroll
      for (int mi = 0; mi < 3; ++mi)
#pragma unroll
        for (int jj = 0; jj < 4; ++jj)
          Sl[mi * 16 + (lane & 15)][ni * 16 + ((lane >> 4) << 2) + jj] = sa[ni][mi][jj];
  } else if (t < 160) {
    const int r = t - 64;
    const float* Tr = (r < 48) ? T1 + (size_t)r * CH : T2 + (size_t)(r - 48) * CH;
    const u16* wr = (r < 48) ? wbf + (size_t)(h * 48 + r) * CH
                             : wbf + (size_t)(384 + h * 48 + (r - 48)) * CH;
    float a = 0.f;
    for (int c4 = 0; c4 < 96; ++c4) {
      f32x4 tv = *(const f32x4*)(Tr + c4 * 4);
      u16x4 wv = *(const u16x4*)(wr + c4 * 4);
#pragma unroll
      for (int jj = 0; jj < 4; ++jj) a = fmaf(tv[jj], bf2f(wv[jj]), a);
    }
    nrm[r] = a;
  }
  __syncthreads();
  if (t < 48) {
    const float th = temp[h];
    const float inq = 1.f / fmaxf(sqrtf(nrm[t]), 1e-12f);
    float l[48];
    float mx = -3.4e38f;
#pragma unroll
    for (int u = 0; u < 48; ++u) {
      float ik = 1.f / fmaxf(sqrtf(nrm[48 + u]), 1e-12f);
      float lg = Sl[t][u] * inq * ik * th;
      l[u] = lg;
      mx = fmaxf(mx, lg);
    }
    float sum = 0.f;
#pragma unroll
    for (int u = 0; u < 48; ++u) { float e = __expf(l[u] - mx); l[u] = e; sum += e; }
    float inv = 1.f / sum;
#pragma unroll
    for (int u = 0; u < 48; ++u) attn[t][u] = l[u] * inv;
  }
  __syncthreads();
  float pw[48];
#pragma unroll
  for (int c = 0; c < 48; ++c) pw[c] = projw[(size_t)t * CH + h * 48 + c];
  u16* Mb = Mbf + ((size_t)b * CH + t) * CH + h * 48;
#pragma unroll 4
  for (int d = 0; d < 48; ++d) {
    float a = 0.f;
#pragma unroll
    for (int c = 0; c < 48; ++c) a = fmaf(pw[c], attn[c][d], a);
    Mb[d] = f2bf(a);
  }
}

// ---- final: out[b] = P_b * xT (ring-3, 3 blocks/CU, XCD chunk swizzle) ------
__global__ __launch_bounds__(256, 3) void k_final(const u16* __restrict__ P,
                                                  const u16* __restrict__ Bx,
                                                  float* __restrict__ outp) {
  constexpr int NWG = 3 * 128 * 4;
  constexpr int CHUNK = NWG / 8;
  const int orig = blockIdx.x;
  const int L = (orig & 7) * CHUNK + (orig >> 3);
  const int ot = L % 3;
  const int ntg = L / 3;
  const int b = ntg >> 7;
  const int nt = ntg & 127;

  __shared__ u16 Ws[3][64 * 64];
  __shared__ u16 Xs[3][64 * 64];
  const int t = threadIdx.x, lane = t & 63, w = t >> 6;
  const int wo = w & 1, wn = w >> 1;
  const u16* Ab = P + (size_t)b * CH * CH + (size_t)ot * 128 * CH;
  const u16* Bb = Bx + (size_t)b * HW * CH + (size_t)nt * 128 * CH;

  f32x4 acc[4][4];
#pragma unroll
  for (int a = 0; a < 4; ++a)
#pragma unroll
    for (int c = 0; c < 4; ++c) acc[a][c] = zero4();

#pragma unroll
  for (int p = 0; p < 2; ++p) {
    stageS<CH>(Ws[p], Ab + p * 32, t);
    stageS<CH>(Xs[p], Bb + p * 32, t);
  }
  const int ks = lane >> 4;
  for (int kt = 0; kt < 12; ++kt) {
    if (kt < 11) asm volatile("s_waitcnt vmcnt(4)" ::: "memory");
    else         asm volatile("s_waitcnt vmcnt(0)" ::: "memory");
    asm volatile("s_barrier" ::: "memory");
    if (kt <= 9) {
      stageS<CH>(Ws[(kt + 2) % 3], Ab + (kt + 2) * 32, t);
      stageS<CH>(Xs[(kt + 2) % 3], Bb + (kt + 2) * 32, t);
    }
    const u16* Wc = Ws[kt % 3];
    const u16* Xc = Xs[kt % 3];
    short8 af[4], bfr[4];
#pragma unroll
    for (int mi = 0; mi < 4; ++mi) {
      const int gr = wo * 64 + mi * 16 + (lane & 15);
      const int r = gr >> 1;
      const int p = ((gr & 1) * 4 + ks) ^ (r & 7);
      af[mi] = *(const short8*)(Wc + r * 64 + p * 8);
    }
#pragma unroll
    for (int ni = 0; ni < 4; ++ni) {
      const int gr = wn * 64 + ni * 16 + (lane & 15);
      const int r = gr >> 1;
      const int p = ((gr & 1) * 4 + ks) ^ (r & 7);
      bfr[ni] = *(const short8*)(Xc + r * 64 + p * 8);
    }
#pragma unroll
    for (int ni = 0; ni < 4; ++ni)
#pragma unroll
      for (int mi = 0; mi < 4; ++mi)
        acc[ni][mi] = mfma_bf16(bfr[ni], af[mi], acc[ni][mi]);
  }
  float* ob = outp + (size_t)b * CH * HW;
#pragma unroll
  for (int ni = 0; ni < 4; ++ni)
#pragma unroll
    for (int mi = 0; mi < 4; ++mi) {
      int o = ot * 128 + wo * 64 + mi * 16 + (lane & 15);
      int n = nt * 128 + wn * 64 + ni * 16 + ((lane >> 4) << 2);
      *(f32x4*)(ob + (size_t)o * HW + n) = acc[ni][mi];
    }
}

extern "C" void kernel_launch(void* const* d_in, const int* in_sizes, int n_in,
                              void* d_out, int out_size, void* d_ws, size_t ws_size,
                              hipStream_t stream) {
  const float* x     = (const float*)d_in[0];
  const float* qkvw  = (const float*)d_in[1];
  const float* projw = (const float*)d_in[2];
  const float* temp  = (const float*)d_in[3];
  float* out = (float*)d_out;
  char* ws = (char*)d_ws;

  // ws layout
  u16*   xT   = (u16*)(ws);                      // 50,331,648
  u16*   wbf  = (u16*)(ws + 50331648);           // 884,736
  u16*   wvt  = (u16*)(ws + 51216384);           // 294,912
  u16*   Goff = (u16*)(ws + 51511296);           // 1,179,648
  float* Gd   = (float*)(ws + 52690944);         // 6,144
  float* Tf   = (float*)(ws + 52697088);         // 4,718,592
  u16*   Mbf  = (u16*)(ws + 57415680);           // 1,179,648
  u16*   Pbf  = (u16*)(ws + 58595328);           // 1,179,648
  // d_out scratch (dead before k_final writes): xb bf16 + gram partials
  u16*   xb   = (u16*)d_out;                     // 50,331,648
  float* part = (float*)((char*)d_out + 50331648);  // 50,331,648

  k_conv<<<dim3(3300), 256, 0, stream>>>(x, xb, qkvw, wbf, wvt);
  k_xform<<<dim3(768 + 3072), 256, 0, stream>>>(xb, part, xT);
  k_greduce<<<dim3(8, 6, 4), 256, 0, stream>>>(part, Goff, Gd);
  k_mini<1><<<dim3(3, 6, 4), 256, 0, stream>>>(wbf, Goff, Tf, nullptr, Gd, wbf);
  k_attn<<<dim3(8, 4), 384, 0, stream>>>(Tf, wbf, projw, temp, Mbf);
  k_mini<0><<<dim3(3, 3, 4), 256, 0, stream>>>(Mbf, wvt, nullptr, Pbf, nullptr, nullptr);
  k_final<<<dim3(3 * 128 * 4), 256, 0, stream>>>(Pbf, xT, out);
}

// Round 17
// 154.102 us; speedup vs baseline: 1.0495x; 1.0495x over previous
//
#include <hip/hip_runtime.h>
#include <stdint.h>

#define HW 16384
#define CH 384
#define NS 32

typedef float  f32x4  __attribute__((ext_vector_type(4)));
typedef short  short8 __attribute__((ext_vector_type(8)));
typedef __bf16 bf16x8 __attribute__((ext_vector_type(8)));
typedef unsigned short u16;
typedef u16 u16x4 __attribute__((ext_vector_type(4)));

__device__ __forceinline__ u16 f2bf(float f) {
  union { float f; uint32_t u; } v; v.f = f;
  uint32_t r = v.u + 0x7fffu + ((v.u >> 16) & 1u);
  return (u16)(r >> 16);
}
__device__ __forceinline__ float bf2f(u16 v) {
  union { uint32_t u; float f; } x; x.u = ((uint32_t)v) << 16; return x.f;
}
__device__ __forceinline__ f32x4 zero4() { f32x4 z = {0.f, 0.f, 0.f, 0.f}; return z; }

__device__ __forceinline__ f32x4 mfma_bf16(short8 a, short8 b, f32x4 c) {
  return __builtin_amdgcn_mfma_f32_16x16x32_bf16(
      __builtin_bit_cast(bf16x8, a), __builtin_bit_cast(bf16x8, b), c, 0, 0, 0);
}

__device__ __forceinline__ void gload16(const void* g, void* lds) {
  auto gp = (const __attribute__((address_space(1))) uint32_t*)(uintptr_t)g;
  auto lp = (__attribute__((address_space(3))) uint32_t*)(uintptr_t)lds;
  __builtin_amdgcn_global_load_lds(gp, lp, 16, 0, 0);
}

// ---- fused: x transpose (blocks 0..6143) + weight convert + WvT -------------
// Transpose: per 64x64 tile, in-register 4x4 transpose -> ds_write_b64 x4;
// LDS pad 66 u16 -> b128 read bank (r+4cc)%32, 2-way (free).
__global__ __launch_bounds__(256) void k_prep_x(const float* __restrict__ x,
                                                u16* __restrict__ xT,
                                                u16* __restrict__ xb,
                                                const float* __restrict__ w,
                                                u16* __restrict__ wbf,
                                                u16* __restrict__ wvt) {
  __shared__ u16 tile[64][66];
  const int bid = blockIdx.x, t = threadIdx.x;
  if (bid >= 6144) {
    if (bid < 7872) {  // 1728 convert blocks
      const int i = (bid - 6144) * 256 + t;
      wbf[i] = f2bf(w[i]);
      return;
    }
    const int q = bid - 7872;  // 36 blocks: WvT[c][d] = w[768+d][c]
    const int ci = q % 6, di = q / 6;
#pragma unroll
    for (int jj = 0; jj < 4; ++jj) {
      const int r = (t >> 4) + jj * 16;
      f32x4 v = *(const f32x4*)(w + (size_t)(768 + di * 64 + r) * CH + ci * 64 + (t & 15) * 4);
#pragma unroll
      for (int i = 0; i < 4; ++i) tile[(t & 15) * 4 + i][r] = f2bf(v[i]);
    }
    __syncthreads();
#pragma unroll
    for (int jj = 0; jj < 2; ++jj) {
      const int c = (t >> 3) + jj * 32;
      short8 v = *(const short8*)(&tile[c][(t & 7) * 8]);
      *(short8*)(wvt + (size_t)(ci * 64 + c) * CH + di * 64 + (t & 7) * 8) = v;
    }
    return;
  }
  const int nt = bid & 255, cq = (bid >> 8) % 6, b = bid / 1536;
  const int c0 = cq * 64, n0 = nt * 64;
  const float* xp = x + (size_t)b * CH * HW;
  u16* xbp = xb + (size_t)b * CH * HW;
  const int nq = t & 15;   // n-quad
  const int cg = t >> 4;   // c-group of 4
  u16 bv[4][4];
#pragma unroll
  for (int i = 0; i < 4; ++i) {
    const int c = c0 + cg * 4 + i;
    f32x4 v = *(const f32x4*)(xp + (size_t)c * HW + n0 + nq * 4);
    u16x4 pk;
#pragma unroll
    for (int j = 0; j < 4; ++j) { bv[i][j] = f2bf(v[j]); pk[j] = bv[i][j]; }
    *(u16x4*)(xbp + (size_t)c * HW + n0 + nq * 4) = pk;
  }
#pragma unroll
  for (int j = 0; j < 4; ++j) {
    u16x4 row = {bv[0][j], bv[1][j], bv[2][j], bv[3][j]};
    *(u16x4*)(&tile[nq * 4 + j][cg * 4]) = row;
  }
  __syncthreads();
  u16* xtb = xT + (size_t)b * HW * CH;
  const int cc = t & 7;
  const int r0 = t >> 3;
#pragma unroll
  for (int jj = 0; jj < 2; ++jj) {
    const int r = r0 + jj * 32;
    short8 v = *(const short8*)(&tile[r][cc * 8]);
    *(short8*)(xtb + (size_t)(n0 + r) * CH + c0 + cc * 8) = v;
  }
}

// ---- stage 128 rows x 32 k, paired-row LDS, proven 0-conflict (R5/R6) -------
template <int STRIDE>
__device__ __forceinline__ void stageS(u16* lds, const u16* __restrict__ g, int t) {
  const int w = t >> 6;
#pragma unroll
  for (int s = 0; s < 2; ++s) {
    const int r = s * 32 + (t >> 3);
    const int g8 = (t & 7) ^ (r & 7);
    const int gr = 2 * r + (g8 >> 2);
    gload16(g + (size_t)gr * STRIDE + (g8 & 3) * 8, lds + s * 2048 + w * 512);
  }
}

// ---- gram of x: G-tile partials via staged ring-3 pipeline ------------------
__global__ __launch_bounds__(256) void k_gramx(const u16* __restrict__ xb,
                                               float* __restrict__ part) {
  const int orig = blockIdx.x;                  // 6*NS*4 = 768, %8==0
  const int L = (orig & 7) * (6 * NS * 4 / 8) + (orig >> 3);  // bijective XCD chunk
  const int pair = L % 6;
  const int ns = (L / 6) % NS;
  const int b = L / (6 * NS);
  const int i = pair < 3 ? 0 : (pair < 5 ? 1 : 2);
  const int j = pair < 3 ? pair : (pair < 5 ? pair - 2 : 2);
  const int t = threadIdx.x, lane = t & 63, w = t >> 6;
  const int wo = w & 1, wn = w >> 1;
  const u16* pa = xb + ((size_t)b * CH + i * 128) * HW + ns * 512;
  const u16* pb = xb + ((size_t)b * CH + j * 128) * HW + ns * 512;

  __shared__ u16 As[3][64 * 64];
  __shared__ u16 Bs[3][64 * 64];

  f32x4 acc[4][4];
#pragma unroll
  for (int a = 0; a < 4; ++a)
#pragma unroll
    for (int c = 0; c < 4; ++c) acc[a][c] = zero4();

#pragma unroll
  for (int p = 0; p < 2; ++p) {
    stageS<HW>(As[p], pa + p * 32, t);
    stageS<HW>(Bs[p], pb + p * 32, t);
  }
  const int ks = lane >> 4;
  for (int kt = 0; kt < 16; ++kt) {
    if (kt < 15) asm volatile("s_waitcnt vmcnt(4)" ::: "memory");
    else         asm volatile("s_waitcnt vmcnt(0)" ::: "memory");
    asm volatile("s_barrier" ::: "memory");
    if (kt <= 13) {
      stageS<HW>(As[(kt + 2) % 3], pa + (kt + 2) * 32, t);
      stageS<HW>(Bs[(kt + 2) % 3], pb + (kt + 2) * 32, t);
    }
    const u16* Ac = As[kt % 3];
    const u16* Bc = Bs[kt % 3];
    short8 af[4], bf[4];
#pragma unroll
    for (int mi = 0; mi < 4; ++mi) {
      const int gr = wo * 64 + mi * 16 + (lane & 15);
      const int r = gr >> 1;
      const int p = ((gr & 1) * 4 + ks) ^ (r & 7);
      af[mi] = *(const short8*)(Ac + r * 64 + p * 8);
    }
#pragma unroll
    for (int ni = 0; ni < 4; ++ni) {
      const int gr = wn * 64 + ni * 16 + (lane & 15);
      const int r = gr >> 1;
      const int p = ((gr & 1) * 4 + ks) ^ (r & 7);
      bf[ni] = *(const short8*)(Bc + r * 64 + p * 8);
    }
#pragma unroll
    for (int ni = 0; ni < 4; ++ni)
#pragma unroll
      for (int mi = 0; mi < 4; ++mi)
        acc[ni][mi] = mfma_bf16(bf[ni], af[mi], acc[ni][mi]);
  }
  float* dst = part + ((size_t)(b * 6 + pair) * NS + ns) * 16384;
#pragma unroll
  for (int ni = 0; ni < 4; ++ni)
#pragma unroll
    for (int mi = 0; mi < 4; ++mi) {
      const int ai = wo * 64 + mi * 16 + (lane & 15);
      const int bj = wn * 64 + ni * 16 + ((lane >> 4) << 2);
      *(f32x4*)(dst + (size_t)ai * 128 + bj) = acc[ni][mi];
    }
}

// ---- reduce partials -> Goff bf16 (diag zeroed, mirrored) + Gd f32 ----------
__global__ __launch_bounds__(256) void k_greduce(const float* __restrict__ part,
                                                 u16* __restrict__ Goff,
                                                 float* __restrict__ Gd) {
  const int cq = blockIdx.x, pair = blockIdx.y, b = blockIdx.z;
  const int i = pair < 3 ? 0 : (pair < 5 ? 1 : 2);
  const int j = pair < 3 ? pair : (pair < 5 ? pair - 2 : 2);
  const int t = threadIdx.x;
  const int c0 = cq * 16;
  __shared__ u16 tl[16][136];
  const float* src = part + (size_t)(b * 6 + pair) * NS * 16384;
#pragma unroll
  for (int p = 0; p < 2; ++p) {
    const int q = t + p * 256;
    const int ai = q >> 2;
    const int bj = c0 + (q & 3) * 4;
    f32x4 s = zero4();
    for (int ns = 0; ns < NS; ++ns) s += *(const f32x4*)(src + (size_t)ns * 16384 + ai * 128 + bj);
    if (i == j) {
#pragma unroll
      for (int jj = 0; jj < 4; ++jj)
        if (ai == bj + jj) { Gd[b * CH + i * 128 + ai] = s[jj]; s[jj] = 0.f; }
    }
    u16x4 pk;
#pragma unroll
    for (int jj = 0; jj < 4; ++jj) { pk[jj] = f2bf(s[jj]); tl[bj - c0 + jj][ai] = pk[jj]; }
    *(u16x4*)(Goff + ((size_t)b * CH + i * 128 + ai) * CH + j * 128 + bj) = pk;
  }
  if (i != j) {
    __syncthreads();
    const int r = t >> 4;
    const int ch = (t & 15) * 8;
    short8 v = *(const short8*)(&tl[r][ch]);
    *(short8*)(Goff + ((size_t)b * CH + j * 128 + c0 + r) * CH + i * 128 + ch) = v;
  }
}

// ---- mini GEMM 128x128, K=384: C = A x B^T (B rows k-contig), ring-4 --------
template <int TM>
__global__ __launch_bounds__(256) void k_mini(const u16* __restrict__ A,
                                              const u16* __restrict__ B,
                                              float* __restrict__ Tout,
                                              u16* __restrict__ Bout,
                                              const float* __restrict__ Gd,
                                              const u16* __restrict__ Wd) {
  const int nt = blockIdx.x, mt = blockIdx.y, b = blockIdx.z;
  __shared__ u16 Ws[4][64 * 64];
  __shared__ u16 Xs[4][64 * 64];
  const int t = threadIdx.x, lane = t & 63, w = t >> 6;
  const int wo = w & 1, wn = w >> 1;
  const u16* Ab = A + (TM ? 0 : (size_t)b * CH * CH) + (size_t)mt * 128 * CH;
  const u16* Bb = B + (TM ? (size_t)b * CH * CH : 0) + (size_t)nt * 128 * CH;

  f32x4 acc[4][4];
#pragma unroll
  for (int a = 0; a < 4; ++a)
#pragma unroll
    for (int c = 0; c < 4; ++c) acc[a][c] = zero4();

#pragma unroll
  for (int p = 0; p < 3; ++p) {
    stageS<CH>(Ws[p], Ab + p * 32, t);
    stageS<CH>(Xs[p], Bb + p * 32, t);
  }
  const int ks = lane >> 4;
  for (int kt = 0; kt < 12; ++kt) {
    if (kt <= 9)       asm volatile("s_waitcnt vmcnt(8)" ::: "memory");
    else if (kt == 10) asm volatile("s_waitcnt vmcnt(4)" ::: "memory");
    else               asm volatile("s_waitcnt vmcnt(0)" ::: "memory");
    asm volatile("s_barrier" ::: "memory");
    if (kt < 9) {
      stageS<CH>(Ws[(kt + 3) & 3], Ab + (kt + 3) * 32, t);
      stageS<CH>(Xs[(kt + 3) & 3], Bb + (kt + 3) * 32, t);
    }
    const u16* Wc = Ws[kt & 3];
    const u16* Xc = Xs[kt & 3];
    short8 af[4], bfr[4];
#pragma unroll
    for (int mi = 0; mi < 4; ++mi) {
      const int gr = wo * 64 + mi * 16 + (lane & 15);
      const int r = gr >> 1;
      const int p = ((gr & 1) * 4 + ks) ^ (r & 7);
      af[mi] = *(const short8*)(Wc + r * 64 + p * 8);
    }
#pragma unroll
    for (int ni = 0; ni < 4; ++ni) {
      const int gr = wn * 64 + ni * 16 + (lane & 15);
      const int r = gr >> 1;
      const int p = ((gr & 1) * 4 + ks) ^ (r & 7);
      bfr[ni] = *(const short8*)(Xc + r * 64 + p * 8);
    }
#pragma unroll
    for (int ni = 0; ni < 4; ++ni)
#pragma unroll
      for (int mi = 0; mi < 4; ++mi)
        acc[ni][mi] = mfma_bf16(bfr[ni], af[mi], acc[ni][mi]);
  }

#pragma unroll
  for (int ni = 0; ni < 4; ++ni)
#pragma unroll
    for (int mi = 0; mi < 4; ++mi) {
      const int tr = mt * 128 + wo * 64 + mi * 16 + (lane & 15);
      const int d0 = nt * 128 + wn * 64 + ni * 16 + ((lane >> 4) << 2);
      if (TM) {
        f32x4 g = *(const f32x4*)(Gd + b * CH + d0);
        u16x4 w4 = *(const u16x4*)(Wd + (size_t)tr * CH + d0);
        f32x4 v;
#pragma unroll
        for (int jj = 0; jj < 4; ++jj) v[jj] = acc[ni][mi][jj] + bf2f(w4[jj]) * g[jj];
        *(f32x4*)(Tout + ((size_t)b * 768 + tr) * CH + d0) = v;
      } else {
        u16x4 pk;
#pragma unroll
        for (int jj = 0; jj < 4; ++jj) pk[jj] = f2bf(acc[ni][mi][jj]);
        *(u16x4*)(Bout + ((size_t)b * CH + tr) * CH + d0) = pk;
      }
    }
}

// ---- per (b,h): S = T1*Wk^T (MFMA, wave0) ; norms ; softmax ; M = proj∘attn -
__global__ __launch_bounds__(384) void k_attn(const float* __restrict__ T,
                                              const u16* __restrict__ wbf,
                                              const float* __restrict__ projw,
                                              const float* __restrict__ temp,
                                              u16* __restrict__ Mbf) {
  const int h = blockIdx.x, b = blockIdx.y, t = threadIdx.x;
  __shared__ float Sl[48][48];
  __shared__ float attn[48][48];
  __shared__ float nrm[96];
  const float* T1 = T + ((size_t)b * 768 + h * 48) * CH;
  const float* T2 = T1 + (size_t)384 * CH;
  const u16* wk = wbf + (size_t)(384 + h * 48) * CH;

  if (t < 64) {
    const int lane = t;
    f32x4 sa[3][3];
#pragma unroll
    for (int a = 0; a < 3; ++a)
#pragma unroll
      for (int c = 0; c < 3; ++c) sa[a][c] = zero4();
    for (int kk = 0; kk < 12; ++kk) {
      const int kc = kk * 32 + ((lane >> 4) << 3);
      short8 afr[3], bfr[3];
#pragma unroll
      for (int mi = 0; mi < 3; ++mi) {
        const float* s = T1 + (size_t)(mi * 16 + (lane & 15)) * CH + kc;
        f32x4 v0 = *(const f32x4*)(s);
        f32x4 v1 = *(const f32x4*)(s + 4);
        short8 a;
#pragma unroll
        for (int jj = 0; jj < 4; ++jj) { a[jj] = (short)f2bf(v0[jj]); a[4 + jj] = (short)f2bf(v1[jj]); }
        afr[mi] = a;
      }
#pragma unroll
      for (int ni = 0; ni < 3; ++ni)
        bfr[ni] = *(const short8*)(wk + (size_t)(ni * 16 + (lane & 15)) * CH + kc);
#pragma unroll
      for (int ni = 0; ni < 3; ++ni)
#pragma unroll
        for (int mi = 0; mi < 3; ++mi)
          sa[ni][mi] = mfma_bf16(bfr[ni], afr[mi], sa[ni][mi]);
    }
#pragma unroll
    for (int ni = 0; ni < 3; ++ni)
#pragma unroll
      for (int mi = 0; mi < 3; ++mi)
#pragma unroll
        for (int jj = 0; jj < 4; ++jj)
          Sl[mi * 16 + (lane & 15)][ni * 16 + ((lane >> 4) << 2) + jj] = sa[ni][mi][jj];
  } else if (t < 160) {
    const int r = t - 64;
    const float* Tr = (r < 48) ? T1 + (size_t)r * CH : T2 + (size_t)(r - 48) * CH;
    const u16* wr = (r < 48) ? wbf + (size_t)(h * 48 + r) * CH
                             : wbf + (size_t)(384 + h * 48 + (r - 48)) * CH;
    float a = 0.f;
    for (int c4 = 0; c4 < 96; ++c4) {
      f32x4 tv = *(const f32x4*)(Tr + c4 * 4);
      u16x4 wv = *(const u16x4*)(wr + c4 * 4);
#pragma unroll
      for (int jj = 0; jj < 4; ++jj) a = fmaf(tv[jj], bf2f(wv[jj]), a);
    }
    nrm[r] = a;
  }
  __syncthreads();
  if (t < 48) {
    const float th = temp[h];
    const float inq = 1.f / fmaxf(sqrtf(nrm[t]), 1e-12f);
    float l[48];
    float mx = -3.4e38f;
#pragma unroll
    for (int u = 0; u < 48; ++u) {
      float ik = 1.f / fmaxf(sqrtf(nrm[48 + u]), 1e-12f);
      float lg = Sl[t][u] * inq * ik * th;
      l[u] = lg;
      mx = fmaxf(mx, lg);
    }
    float sum = 0.f;
#pragma unroll
    for (int u = 0; u < 48; ++u) { float e = __expf(l[u] - mx); l[u] = e; sum += e; }
    float inv = 1.f / sum;
#pragma unroll
    for (int u = 0; u < 48; ++u) attn[t][u] = l[u] * inv;
  }
  __syncthreads();
  float pw[48];
#pragma unroll
  for (int c = 0; c < 48; ++c) pw[c] = projw[(size_t)t * CH + h * 48 + c];
  u16* Mb = Mbf + ((size_t)b * CH + t) * CH + h * 48;
#pragma unroll 4
  for (int d = 0; d < 48; ++d) {
    float a = 0.f;
#pragma unroll
    for (int c = 0; c < 48; ++c) a = fmaf(pw[c], attn[c][d], a);
    Mb[d] = f2bf(a);
  }
}

// ---- final: out[b] = P_b * xT (ring-3, 3 blocks/CU, XCD chunk swizzle) ------
__global__ __launch_bounds__(256, 3) void k_final(const u16* __restrict__ P,
                                                  const u16* __restrict__ Bx,
                                                  float* __restrict__ outp) {
  constexpr int NWG = 3 * 128 * 4;
  constexpr int CHUNK = NWG / 8;
  const int orig = blockIdx.x;
  const int L = (orig & 7) * CHUNK + (orig >> 3);
  const int ot = L % 3;
  const int ntg = L / 3;
  const int b = ntg >> 7;
  const int nt = ntg & 127;

  __shared__ u16 Ws[3][64 * 64];
  __shared__ u16 Xs[3][64 * 64];
  const int t = threadIdx.x, lane = t & 63, w = t >> 6;
  const int wo = w & 1, wn = w >> 1;
  const u16* Ab = P + (size_t)b * CH * CH + (size_t)ot * 128 * CH;
  const u16* Bb = Bx + (size_t)b * HW * CH + (size_t)nt * 128 * CH;

  f32x4 acc[4][4];
#pragma unroll
  for (int a = 0; a < 4; ++a)
#pragma unroll
    for (int c = 0; c < 4; ++c) acc[a][c] = zero4();

#pragma unroll
  for (int p = 0; p < 2; ++p) {
    stageS<CH>(Ws[p], Ab + p * 32, t);
    stageS<CH>(Xs[p], Bb + p * 32, t);
  }
  const int ks = lane >> 4;
  for (int kt = 0; kt < 12; ++kt) {
    if (kt < 11) asm volatile("s_waitcnt vmcnt(4)" ::: "memory");
    else         asm volatile("s_waitcnt vmcnt(0)" ::: "memory");
    asm volatile("s_barrier" ::: "memory");
    if (kt <= 9) {
      stageS<CH>(Ws[(kt + 2) % 3], Ab + (kt + 2) * 32, t);
      stageS<CH>(Xs[(kt + 2) % 3], Bb + (kt + 2) * 32, t);
    }
    const u16* Wc = Ws[kt % 3];
    const u16* Xc = Xs[kt % 3];
    short8 af[4], bfr[4];
#pragma unroll
    for (int mi = 0; mi < 4; ++mi) {
      const int gr = wo * 64 + mi * 16 + (lane & 15);
      const int r = gr >> 1;
      const int p = ((gr & 1) * 4 + ks) ^ (r & 7);
      af[mi] = *(const short8*)(Wc + r * 64 + p * 8);
    }
#pragma unroll
    for (int ni = 0; ni < 4; ++ni) {
      const int gr = wn * 64 + ni * 16 + (lane & 15);
      const int r = gr >> 1;
      const int p = ((gr & 1) * 4 + ks) ^ (r & 7);
      bfr[ni] = *(const short8*)(Xc + r * 64 + p * 8);
    }
#pragma unroll
    for (int ni = 0; ni < 4; ++ni)
#pragma unroll
      for (int mi = 0; mi < 4; ++mi)
        acc[ni][mi] = mfma_bf16(bfr[ni], af[mi], acc[ni][mi]);
  }
  float* ob = outp + (size_t)b * CH * HW;
#pragma unroll
  for (int ni = 0; ni < 4; ++ni)
#pragma unroll
    for (int mi = 0; mi < 4; ++mi) {
      int o = ot * 128 + wo * 64 + mi * 16 + (lane & 15);
      int n = nt * 128 + wn * 64 + ni * 16 + ((lane >> 4) << 2);
      *(f32x4*)(ob + (size_t)o * HW + n) = acc[ni][mi];
    }
}

extern "C" void kernel_launch(void* const* d_in, const int* in_sizes, int n_in,
                              void* d_out, int out_size, void* d_ws, size_t ws_size,
                              hipStream_t stream) {
  const float* x     = (const float*)d_in[0];
  const float* qkvw  = (const float*)d_in[1];
  const float* projw = (const float*)d_in[2];
  const float* temp  = (const float*)d_in[3];
  float* out = (float*)d_out;
  char* ws = (char*)d_ws;

  // ws layout
  u16*   xT   = (u16*)(ws);                      // 50,331,648
  u16*   wbf  = (u16*)(ws + 50331648);           // 884,736
  u16*   wvt  = (u16*)(ws + 51216384);           // 294,912
  u16*   Goff = (u16*)(ws + 51511296);           // 1,179,648
  float* Gd   = (float*)(ws + 52690944);         // 6,144
  float* Tf   = (float*)(ws + 52697088);         // 4,718,592
  u16*   Mbf  = (u16*)(ws + 57415680);           // 1,179,648
  u16*   Pbf  = (u16*)(ws + 58595328);           // 1,179,648
  // d_out scratch (dead before k_final writes): xb bf16 + gram partials
  u16*   xb   = (u16*)d_out;                     // 50,331,648
  float* part = (float*)((char*)d_out + 50331648);  // 50,331,648

  k_prep_x<<<dim3(7908), 256, 0, stream>>>(x, xT, xb, qkvw, wbf, wvt);
  k_gramx<<<dim3(6 * NS * 4), 256, 0, stream>>>(xb, part);
  k_greduce<<<dim3(8, 6, 4), 256, 0, stream>>>(part, Goff, Gd);
  k_mini<1><<<dim3(3, 6, 4), 256, 0, stream>>>(wbf, Goff, Tf, nullptr, Gd, wbf);
  k_attn<<<dim3(8, 4), 384, 0, stream>>>(Tf, wbf, projw, temp, Mbf);
  k_mini<0><<<dim3(3, 3, 4), 256, 0, stream>>>(Mbf, wvt, nullptr, Pbf, nullptr, nullptr);
  k_final<<<dim3(3 * 128 * 4), 256, 0, stream>>>(Pbf, xT, out);
}